// Round 7
// baseline (760.857 us; speedup 1.0000x reference)
//
#include <hip/hip_runtime.h>

#define N_NODES 100000
#define N_EDGES 3200000
#define D_IN    512
#define D_HID   16
#define N_CLS   7
#define D_PAD   8

#define NB        512                 // dst-range buckets
#define NODES_PER 196                 // ceil(N_NODES / NB)
#define BCAP      8192                // per-bucket capacity (mean 6272, +24 sigma)
#define FILL_CHUNK 16384
#define FILL_WGS  ((N_EDGES + FILL_CHUNK - 1) / FILL_CHUNK)   // 196

// ---------------- cursor init: cursor[b] = b * BCAP ----------------
__global__ __launch_bounds__(512) void cursor_init(int* __restrict__ cursor) {
    cursor[threadIdx.x] = (int)threadIdx.x * BCAP;
}

// ---------------- bucket fill: packed[slot] = src | (local_dst << 17) -------
__global__ __launch_bounds__(1024) void bucket_fill(const int* __restrict__ src,
                                                    const int* __restrict__ dst,
                                                    int* __restrict__ cursor,
                                                    unsigned int* __restrict__ packed) {
    __shared__ int bcnt[NB];
    __shared__ int bcur[NB];
    int t = threadIdx.x;
    if (t < NB) bcnt[t] = 0;
    __syncthreads();

    int base_e = blockIdx.x * FILL_CHUNK;
#pragma unroll
    for (int i = 0; i < FILL_CHUNK / 1024; ++i) {
        int e = base_e + i * 1024 + t;
        if (e < N_EDGES) atomicAdd(&bcnt[dst[e] / NODES_PER], 1);
    }
    __syncthreads();

    if (t < NB) {
        int c = bcnt[t];
        bcur[t] = (c > 0) ? atomicAdd(&cursor[t], c) : 0;
    }
    __syncthreads();

#pragma unroll
    for (int i = 0; i < FILL_CHUNK / 1024; ++i) {
        int e = base_e + i * 1024 + t;
        if (e < N_EDGES) {
            int d = dst[e];
            int b = d / NODES_PER;
            int loc = d - b * NODES_PER;
            int r = atomicAdd(&bcur[b], 1);
            packed[r] = (unsigned)src[e] | ((unsigned)loc << 17);
        }
    }
}

// ---------------- h1 = x @ W1  (100000x512 @ 512x16) ----------------
__global__ __launch_bounds__(256) void gemm1(const float* __restrict__ x,
                                             const float* __restrict__ W1,
                                             float* __restrict__ h1) {
    __shared__ float4 w4s[D_IN * 4];          // 32 KB
    const float4* W1f4 = (const float4*)W1;
    int t = threadIdx.x;
#pragma unroll
    for (int i = 0; i < 8; ++i) w4s[i * 256 + t] = W1f4[i * 256 + t];
    __syncthreads();

    int jq  = t & 3;
    int r   = t >> 2;
    int row = blockIdx.x * 64 + r;
    if (row >= N_NODES) return;

    const float4* xr = (const float4*)(x + (size_t)row * D_IN);
    float4 acc = make_float4(0.f, 0.f, 0.f, 0.f);

#pragma unroll 4
    for (int k4 = 0; k4 < D_IN / 4; ++k4) {
        float4 xv = xr[k4];
        float4 w0 = w4s[(k4 * 4 + 0) * 4 + jq];
        float4 w1 = w4s[(k4 * 4 + 1) * 4 + jq];
        float4 w2 = w4s[(k4 * 4 + 2) * 4 + jq];
        float4 w3 = w4s[(k4 * 4 + 3) * 4 + jq];
        acc.x = fmaf(xv.x, w0.x, acc.x); acc.y = fmaf(xv.x, w0.y, acc.y);
        acc.z = fmaf(xv.x, w0.z, acc.z); acc.w = fmaf(xv.x, w0.w, acc.w);
        acc.x = fmaf(xv.y, w1.x, acc.x); acc.y = fmaf(xv.y, w1.y, acc.y);
        acc.z = fmaf(xv.y, w1.z, acc.z); acc.w = fmaf(xv.y, w1.w, acc.w);
        acc.x = fmaf(xv.z, w2.x, acc.x); acc.y = fmaf(xv.z, w2.y, acc.y);
        acc.z = fmaf(xv.z, w2.z, acc.z); acc.w = fmaf(xv.z, w2.w, acc.w);
        acc.x = fmaf(xv.w, w3.x, acc.x); acc.y = fmaf(xv.w, w3.y, acc.y);
        acc.z = fmaf(xv.w, w3.z, acc.z); acc.w = fmaf(xv.w, w3.w, acc.w);
    }
    ((float4*)(h1 + (size_t)row * D_HID))[jq] = acc;
}

// -------- agg1 (LDS accumulate, LDS-staged edges, 4x-unrolled gathers)
//          fused with layer2: h2p = pad8(relu(agg+b1)@W2) --------------------
__global__ __launch_bounds__(1024) void agg1_layer2(const unsigned int* __restrict__ packed,
                                                    const int* __restrict__ cursor,
                                                    const float* __restrict__ h1,
                                                    const float* __restrict__ b1,
                                                    const float* __restrict__ W2,
                                                    float* __restrict__ h2p) {
    __shared__ float acc[NODES_PER * D_HID];   // 12.5 KB
    __shared__ unsigned eld[BCAP];             // 32 KB staged edge list
    __shared__ float w2s[D_HID * N_CLS];
    __shared__ float b1s[D_HID];
    int t = threadIdx.x;
    int b = blockIdx.x;
    int e0 = b * BCAP;
    int cnt = cursor[b] - e0;

    // cooperative coalesced stage of this bucket's packed edges
    const uint4* ps = (const uint4*)(packed + e0);
    int n4 = (cnt + 3) >> 2;
    for (int i = t; i < n4; i += 1024) ((uint4*)eld)[i] = ps[i];

    if (t < D_HID * N_CLS) w2s[t] = W2[t];
    if (t >= 128 && t < 128 + D_HID) b1s[t - 128] = b1[t - 128];
    for (int i = t; i < NODES_PER * D_HID; i += 1024) acc[i] = 0.f;
    __syncthreads();

    // 64 lane-groups of 16; each owns a contiguous chunk; 4 gathers in flight
    int g = t >> 4, j = t & 15;
    int chunk = (cnt + 63) >> 6;
    int k  = g * chunk;
    int ke = k + chunk; if (ke > cnt) ke = cnt;
    for (; k + 3 < ke; k += 4) {
        unsigned p0 = eld[k], p1 = eld[k + 1], p2 = eld[k + 2], p3 = eld[k + 3];
        float f0 = h1[(size_t)(p0 & 0x1FFFF) * D_HID + j];
        float f1 = h1[(size_t)(p1 & 0x1FFFF) * D_HID + j];
        float f2 = h1[(size_t)(p2 & 0x1FFFF) * D_HID + j];
        float f3 = h1[(size_t)(p3 & 0x1FFFF) * D_HID + j];
        atomicAdd(&acc[(p0 >> 17) * D_HID + j], f0);
        atomicAdd(&acc[(p1 >> 17) * D_HID + j], f1);
        atomicAdd(&acc[(p2 >> 17) * D_HID + j], f2);
        atomicAdd(&acc[(p3 >> 17) * D_HID + j], f3);
    }
    for (; k < ke; ++k) {
        unsigned p = eld[k];
        atomicAdd(&acc[(p >> 17) * D_HID + j], h1[(size_t)(p & 0x1FFFF) * D_HID + j]);
    }
    __syncthreads();

    // fused layer2 epilogue
    int nbase = b * NODES_PER;
    int nn = N_NODES - nbase; if (nn > NODES_PER) nn = NODES_PER;
    if ((int)t < nn) {
        float o[N_CLS];
#pragma unroll
        for (int c = 0; c < N_CLS; ++c) o[c] = 0.f;
#pragma unroll
        for (int jj = 0; jj < D_HID; ++jj) {
            float r = fmaxf(acc[t * D_HID + jj] + b1s[jj], 0.f);
#pragma unroll
            for (int c = 0; c < N_CLS; ++c)
                o[c] = fmaf(r, w2s[jj * N_CLS + c], o[c]);
        }
        float4* hp = (float4*)(h2p + (size_t)(nbase + t) * D_PAD);
        hp[0] = make_float4(o[0], o[1], o[2], o[3]);
        hp[1] = make_float4(o[4], o[5], o[6], 0.f);
    }
}

// -------- agg2 (LDS accumulate, LDS-staged edges, 4x-unrolled) + b2 ---------
__global__ __launch_bounds__(1024) void agg2_out(const unsigned int* __restrict__ packed,
                                                 const int* __restrict__ cursor,
                                                 const float* __restrict__ h2p,
                                                 const float* __restrict__ b2,
                                                 float* __restrict__ out) {
    __shared__ float acc[NODES_PER * D_PAD];   // 6.3 KB
    __shared__ unsigned eld[BCAP];             // 32 KB
    __shared__ float b2s[N_CLS];
    int t = threadIdx.x;
    int b = blockIdx.x;
    int e0 = b * BCAP;
    int cnt = cursor[b] - e0;

    const uint4* ps = (const uint4*)(packed + e0);
    int n4 = (cnt + 3) >> 2;
    for (int i = t; i < n4; i += 1024) ((uint4*)eld)[i] = ps[i];

    if (t < N_CLS) b2s[t] = b2[t];
    for (int i = t; i < NODES_PER * D_PAD; i += 1024) acc[i] = 0.f;
    __syncthreads();

    // 128 lane-groups of 8; contiguous chunks; 4 gathers in flight
    int g = t >> 3, j = t & 7;
    int chunk = (cnt + 127) >> 7;
    int k  = g * chunk;
    int ke = k + chunk; if (ke > cnt) ke = cnt;
    for (; k + 3 < ke; k += 4) {
        unsigned p0 = eld[k], p1 = eld[k + 1], p2 = eld[k + 2], p3 = eld[k + 3];
        float f0 = h2p[(size_t)(p0 & 0x1FFFF) * D_PAD + j];
        float f1 = h2p[(size_t)(p1 & 0x1FFFF) * D_PAD + j];
        float f2 = h2p[(size_t)(p2 & 0x1FFFF) * D_PAD + j];
        float f3 = h2p[(size_t)(p3 & 0x1FFFF) * D_PAD + j];
        atomicAdd(&acc[(p0 >> 17) * D_PAD + j], f0);
        atomicAdd(&acc[(p1 >> 17) * D_PAD + j], f1);
        atomicAdd(&acc[(p2 >> 17) * D_PAD + j], f2);
        atomicAdd(&acc[(p3 >> 17) * D_PAD + j], f3);
    }
    for (; k < ke; ++k) {
        unsigned p = eld[k];
        atomicAdd(&acc[(p >> 17) * D_PAD + j], h2p[(size_t)(p & 0x1FFFF) * D_PAD + j]);
    }
    __syncthreads();

    int nbase = b * NODES_PER;
    int nn = N_NODES - nbase; if (nn > NODES_PER) nn = NODES_PER;
    if (nn > 0) {
        int total = nn * N_CLS;
        float* obase = out + (size_t)nbase * N_CLS;
        for (int i = t; i < total; i += 1024) {
            int node = i / N_CLS;
            int c = i - node * N_CLS;
            obase[i] = acc[node * D_PAD + c] + b2s[c];
        }
    }
}

extern "C" void kernel_launch(void* const* d_in, const int* in_sizes, int n_in,
                              void* d_out, int out_size, void* d_ws, size_t ws_size,
                              hipStream_t stream) {
    const float* x  = (const float*)d_in[0];
    const int*   ei = (const int*)d_in[1];
    const float* W1 = (const float*)d_in[2];
    const float* b1 = (const float*)d_in[3];
    const float* W2 = (const float*)d_in[4];
    const float* b2 = (const float*)d_in[5];
    float* out = (float*)d_out;

    char* ws = (char*)d_ws;
    float*        h1     = (float*)(ws);                       //  6,400,000 B
    float*        h2p    = (float*)(ws + 6400000);             //  3,200,000 B
    unsigned int* packed = (unsigned int*)(ws + 9600000);      // 16,777,216 B
    int*          cursor = (int*)(ws + 26377216);              //      2,048 B

    const int* src = ei;             // edge_index[0]
    const int* dst = ei + N_EDGES;   // edge_index[1]

    cursor_init<<<1, 512, 0, stream>>>(cursor);
    bucket_fill<<<FILL_WGS, 1024, 0, stream>>>(src, dst, cursor, packed);
    gemm1<<<(N_NODES + 63) / 64, 256, 0, stream>>>(x, W1, h1);
    agg1_layer2<<<NB, 1024, 0, stream>>>(packed, cursor, h1, b1, W2, h2p);
    agg2_out<<<NB, 1024, 0, stream>>>(packed, cursor, h2p, b2, out);
}